// Round 16
// baseline (16322.733 us; speedup 1.0000x reference)
//
#include <hip/hip_runtime.h>

// SingleLayerRNN — Round 16: h reads via plain bypass loads (read path),
// not atomic ops. R13-R15 evidence: __hip_atomic_load at agent/system scope
// puts 16.5MB/step of h traffic on the EA WRITE path (8.46GB/dispatch,
// ~516GB/s => the whole kernel time). This round: inline-asm
// global_load_dwordx4 sc0 sc1 (bypass L1/L2, read at MALL) batched 8-wide
// with a single vmcnt(0). Stores/publish/poll unchanged (R15-proven).
//
// FROZEN arithmetic (R8, absmax=0.0):
//   cx0 = FMA chain k=0..511 of x[b,k]*Wih[k,j] (ascending, single acc)
//   cx1 = chain k=512..1023; ch0/ch1 = same over h,Whh
//   s = (cx0+cx1)+(ch0+ch1); h' = tanh_T2(s)  [XLA fast-tanh FMA form]

#define TSTEPS 512
#define BATCH  64
#define HID    1024
#define NELEM  65536
#define LROW   1028     // LDS row stride (floats): 16B-aligned, bank-spread

typedef float f32x4 __attribute__((ext_vector_type(4)));

__device__ __forceinline__ float tanh_T2(float x) {
#pragma clang fp contract(off)
    const float C = 7.99881172180175781f;
    float ax = fabsf(x);
    float xc = fminf(fmaxf(x, -C), C);
    float x2 = xc * xc;
    float num = -2.76076847742355e-16f;
    num = __builtin_fmaf(x2, num, 2.00018790482477e-13f);
    num = __builtin_fmaf(x2, num, -8.60467152213735e-11f);
    num = __builtin_fmaf(x2, num, 5.12229709037114e-08f);
    num = __builtin_fmaf(x2, num, 1.48572235717979e-05f);
    num = __builtin_fmaf(x2, num, 6.37261928875436e-04f);
    num = __builtin_fmaf(x2, num, 4.89352455891786e-03f);
    num = xc * num;
    float den = 1.19825839466702e-06f;
    den = __builtin_fmaf(x2, den, 1.18534705686654e-04f);
    den = __builtin_fmaf(x2, den, 2.26843463243900e-03f);
    den = __builtin_fmaf(x2, den, 4.89352518554385e-03f);
    float r = num / den;
    return (ax < 0.0004f) ? x : r;
}

// W [k][j] -> WT [j][k]  (bit-exact data movement; verified R10/R12-R15)
__global__ __launch_bounds__(256) void transpose_w(const float* __restrict__ W,
                                                   float* __restrict__ WT) {
    __shared__ float tile[64][65];
    const int c0 = blockIdx.x * 64;
    const int r0 = blockIdx.y * 64;
    const int tx = threadIdx.x & 63;
    const int ty = threadIdx.x >> 6;
    #pragma unroll
    for (int r = 0; r < 16; ++r) {
        const int rr = r * 4 + ty;
        tile[rr][tx] = W[(size_t)(r0 + rr) * HID + c0 + tx];
    }
    __syncthreads();
    #pragma unroll
    for (int r = 0; r < 16; ++r) {
        const int rr = r * 4 + ty;
        WT[(size_t)(c0 + rr) * HID + r0 + tx] = tile[tx][rr];
    }
}

__global__ __launch_bounds__(256, 2) void rnn_persist6(
    const float* __restrict__ x,      // [512][64][1024]
    const float* __restrict__ WTih,   // [j][k]
    const float* __restrict__ WThh,   // [j][k]
    float* __restrict__ hb0,
    float* __restrict__ hb1,
    unsigned int* __restrict__ cnt,   // 8 group counters, 128B apart
    float* __restrict__ out)
{
#pragma clang fp contract(off)
    __shared__ float lds_x[8 * LROW];
    __shared__ float lds_h[8 * LROW];
    __shared__ float pl[4][8][16];    // [mat*2+half][b][j]

    const int slice  = blockIdx.x & 7;     // j-slice -> XCD (round-robin)
    const int wid    = blockIdx.x >> 3;    // 0..63
    const int bchunk = wid >> 3;           // 0..7  (8 batch rows each)
    const int jchunk = wid & 7;            // 0..7  (16 j cols each)
    const int tid  = threadIdx.x;
    const int jl   = tid & 15;
    const int bp   = (tid >> 4) & 3;
    const int half = (tid >> 6) & 1;
    const int mat  = tid >> 7;             // wave-uniform
    const int jglob = slice * 128 + jchunk * 16 + jl;
    const int b0 = 2 * bp;

    const float* wrow = ((mat == 0) ? WTih : WThh)
                      + (size_t)jglob * HID + half * 512;
    float* hb[2] = { hb0, hb1 };
    unsigned int* mycnt = &cnt[bchunk * 32];

    for (int t = 0; t < TSTEPS; ++t) {
        // ---- prefetch x_t into registers (independent of h_t) ----
        float4 xv[8];
        {
            const float* xsrc = x + (size_t)t * NELEM
                              + (size_t)(bchunk * 8) * HID;
            #pragma unroll
            for (int u = 0; u < 8; ++u) {
                const int i = tid + u * 256;
                const int r = i >> 8, c4 = i & 255;
                xv[u] = ((const float4*)(xsrc + (size_t)r * HID))[c4];
            }
        }

        // ---- group barrier: all 64 blocks of this bchunk at step t ----
        if (t > 0) {
            if (tid == 0) {
                const unsigned target = 64u * (unsigned)t;
                while (__hip_atomic_load(mycnt, __ATOMIC_RELAXED,
                                         __HIP_MEMORY_SCOPE_AGENT) < target)
                    __builtin_amdgcn_s_sleep(1);
            }
            __syncthreads();
        }

        // ---- stage: x regs->LDS; h via PLAIN bypass reads (sc0 sc1) ----
        #pragma unroll
        for (int u = 0; u < 8; ++u) {
            const int i = tid + u * 256;
            const int r = i >> 8, c4 = i & 255;
            *(float4*)&lds_x[r * LROW + c4 * 4] = xv[u];
        }
        if (t > 0) {
            const float* hsrc = hb[t & 1] + (size_t)(bchunk * 8) * HID;
            // thread's 8 x dwordx4: i4 = tid + u*256 (0..2047); r = i4>>8,
            // kq = i4&255 -> 16B-contiguous, row-major over 8 rows.
            const float* a0 = hsrc + (size_t)((tid + 0*256) >> 8) * HID + ((tid + 0*256) & 255) * 4;
            const float* a1 = hsrc + (size_t)((tid + 1*256) >> 8) * HID + ((tid + 1*256) & 255) * 4;
            const float* a2 = hsrc + (size_t)((tid + 2*256) >> 8) * HID + ((tid + 2*256) & 255) * 4;
            const float* a3 = hsrc + (size_t)((tid + 3*256) >> 8) * HID + ((tid + 3*256) & 255) * 4;
            const float* a4 = hsrc + (size_t)((tid + 4*256) >> 8) * HID + ((tid + 4*256) & 255) * 4;
            const float* a5 = hsrc + (size_t)((tid + 5*256) >> 8) * HID + ((tid + 5*256) & 255) * 4;
            const float* a6 = hsrc + (size_t)((tid + 6*256) >> 8) * HID + ((tid + 6*256) & 255) * 4;
            const float* a7 = hsrc + (size_t)((tid + 7*256) >> 8) * HID + ((tid + 7*256) & 255) * 4;
            f32x4 h0, h1, h2, h3, h4, h5, h6, h7;
            asm volatile(
                "global_load_dwordx4 %0, %8, off sc0 sc1\n\t"
                "global_load_dwordx4 %1, %9, off sc0 sc1\n\t"
                "global_load_dwordx4 %2, %10, off sc0 sc1\n\t"
                "global_load_dwordx4 %3, %11, off sc0 sc1\n\t"
                "global_load_dwordx4 %4, %12, off sc0 sc1\n\t"
                "global_load_dwordx4 %5, %13, off sc0 sc1\n\t"
                "global_load_dwordx4 %6, %14, off sc0 sc1\n\t"
                "global_load_dwordx4 %7, %15, off sc0 sc1\n\t"
                "s_waitcnt vmcnt(0)"
                : "=&v"(h0), "=&v"(h1), "=&v"(h2), "=&v"(h3),
                  "=&v"(h4), "=&v"(h5), "=&v"(h6), "=&v"(h7)
                : "v"(a0), "v"(a1), "v"(a2), "v"(a3),
                  "v"(a4), "v"(a5), "v"(a6), "v"(a7)
                : "memory");
            #pragma unroll
            for (int u = 0; u < 8; ++u) {
                const int i4 = tid + u * 256;
                const int r = i4 >> 8, kq = (i4 & 255) * 4;
                const f32x4 hv = (u == 0) ? h0 : (u == 1) ? h1 : (u == 2) ? h2
                               : (u == 3) ? h3 : (u == 4) ? h4 : (u == 5) ? h5
                               : (u == 6) ? h6 : h7;
                *(f32x4*)&lds_h[r * LROW + kq] = hv;
            }
        }
        __syncthreads();

        // ---- chains (frozen order; two b-rows share each W value) ----
        float acc0 = 0.0f, acc1 = 0.0f;
        if (mat == 0 || t > 0) {
            const float* base = (mat == 0) ? lds_x : lds_h;
            const float* oa = base + b0 * LROW;
            const float* ob = base + (b0 + 1) * LROW;
            const float4* w4 = (const float4*)wrow;
            const int kbase = half * 512;
            #pragma unroll 4
            for (int kq = 0; kq < 128; ++kq) {
                const float4 w = w4[kq];
                const int k = kbase + kq * 4;
                acc0 = __builtin_fmaf(oa[k + 0], w.x, acc0);
                acc1 = __builtin_fmaf(ob[k + 0], w.x, acc1);
                acc0 = __builtin_fmaf(oa[k + 1], w.y, acc0);
                acc1 = __builtin_fmaf(ob[k + 1], w.y, acc1);
                acc0 = __builtin_fmaf(oa[k + 2], w.z, acc0);
                acc1 = __builtin_fmaf(ob[k + 2], w.z, acc1);
                acc0 = __builtin_fmaf(oa[k + 3], w.w, acc0);
                acc1 = __builtin_fmaf(ob[k + 3], w.w, acc1);
            }
        }
        pl[mat * 2 + half][b0][jl]     = acc0;
        pl[mat * 2 + half][b0 + 1][jl] = acc1;
        __syncthreads();

        // ---- combine (frozen order) + publish h_{t+1} ----
        if (tid < 128) {
            const int b = tid >> 4, j = tid & 15;
            const float dotX = pl[0][b][j] + pl[1][b][j];   // cx0 + cx1
            const float dotH = pl[2][b][j] + pl[3][b][j];   // ch0 + ch1
            const float hv = tanh_T2(dotX + dotH);
            const size_t o = (size_t)(bchunk * 8 + b) * HID
                           + (size_t)slice * 128 + (size_t)jchunk * 16 + j;
            if (t + 1 < TSTEPS)
                __hip_atomic_store(&hb[(t + 1) & 1][o], hv, __ATOMIC_RELAXED,
                                   __HIP_MEMORY_SCOPE_AGENT);
            else
                out[o] = hv;
        }
        __syncthreads();   // vmcnt(0): h stores complete at MALL before arrival

        // ---- publish arrival: relaxed device-scope add ----
        if (t + 1 < TSTEPS && tid == 0)
            __hip_atomic_fetch_add(mycnt, 1u, __ATOMIC_RELAXED,
                                   __HIP_MEMORY_SCOPE_AGENT);
    }
}

// ---- proven fallback (R8): 512 launches, 512KB ws ----
__global__ __launch_bounds__(256) void rnn_step_r8(
    const float* __restrict__ xt, const float* __restrict__ Wih,
    const float* __restrict__ Whh, const float* __restrict__ hin,
    float* __restrict__ hout)
{
#pragma clang fp contract(off)
    __shared__ float xs[4 * HID];
    __shared__ float hs[4 * HID];
    const int jb = blockIdx.x * 64;
    const int ib = blockIdx.y * 4;
    for (int idx = threadIdx.x; idx < 4 * HID; idx += 256) {
        xs[idx] = xt[ib * HID + idx];
        hs[idx] = hin ? hin[ib * HID + idx] : 0.0f;
    }
    __syncthreads();
    const int jl = threadIdx.x & 63;
    const int i  = threadIdx.x >> 6;
    const int j  = jb + jl;
    const float* xr = xs + i * HID;
    const float* hr = hs + i * HID;
    float cx0 = 0.f, cx1 = 0.f, ch0 = 0.f, ch1 = 0.f;
    #pragma unroll 8
    for (int k = 0; k < 512; ++k) {
        cx0 = __builtin_fmaf(xr[k], Wih[(size_t)k * HID + j], cx0);
        ch0 = __builtin_fmaf(hr[k], Whh[(size_t)k * HID + j], ch0);
    }
    #pragma unroll 8
    for (int k = 512; k < 1024; ++k) {
        cx1 = __builtin_fmaf(xr[k], Wih[(size_t)k * HID + j], cx1);
        ch1 = __builtin_fmaf(hr[k], Whh[(size_t)k * HID + j], ch1);
    }
    const float s = (cx0 + cx1) + (ch0 + ch1);
    hout[(size_t)(ib + i) * HID + j] = tanh_T2(s);
}

extern "C" void kernel_launch(void* const* d_in, const int* in_sizes, int n_in,
                              void* d_out, int out_size, void* d_ws, size_t ws_size,
                              hipStream_t stream) {
    const float* x   = (const float*)d_in[0];
    const float* Wih = (const float*)d_in[1];
    const float* Whh = (const float*)d_in[2];
    float* out = (float*)d_out;

    const size_t wT = (size_t)HID * HID;
    const size_t need = (2 * wT + 2 * (size_t)NELEM) * sizeof(float)
                      + 8 * 32 * sizeof(unsigned int);    // ~8.5 MB
    if (ws_size >= need) {
        float* WTih = (float*)d_ws;
        float* WThh = WTih + wT;
        float* hb0  = WThh + wT;
        float* hb1  = hb0 + NELEM;
        unsigned int* cnt = (unsigned int*)(hb1 + NELEM);

        transpose_w<<<dim3(16, 16), 256, 0, stream>>>(Wih, WTih);
        transpose_w<<<dim3(16, 16), 256, 0, stream>>>(Whh, WThh);
        hipMemsetAsync(cnt, 0, 8 * 32 * sizeof(unsigned int), stream);

        rnn_persist6<<<dim3(512), dim3(256), 0, stream>>>(
            x, WTih, WThh, hb0, hb1, cnt, out);
    } else {
        float* buf0 = (float*)d_ws;
        float* buf1 = buf0 + NELEM;
        const dim3 grid(HID / 64, BATCH / 4), block(256);
        for (int t = 0; t < TSTEPS; ++t) {
            const float* hin = (t == 0) ? nullptr
                              : ((t & 1) ? buf0 : buf1);
            float* hout = (t == TSTEPS - 1) ? out
                         : ((t & 1) ? buf1 : buf0);
            rnn_step_r8<<<grid, block, 0, stream>>>(
                x + (size_t)t * NELEM, Wih, Whh, hin, hout);
        }
    }
}